// Round 10
// baseline (319.142 us; speedup 1.0000x reference)
//
#include <hip/hip_runtime.h>

#define NN 30000
#define EE 300000
#define HH 4
#define SLOPE 0.2f
#define SCAN_NB 15        // ceil(30000 / 2048)

typedef _Float16 f16;
struct f16x2 { f16 x, y; };
typedef f16 f16x8 __attribute__((ext_vector_type(8)));
typedef float f32x4 __attribute__((ext_vector_type(4)));

// ---------------- zero deg ----------------
__global__ __launch_bounds__(256) void zero_k(int4* __restrict__ p, int n4) {
    const int i = blockIdx.x * 256 + threadIdx.x;
    if (i < n4) p[i] = make_int4(0, 0, 0, 0);
}

// ---------------- x -> f16 (once per call) ----------------
__global__ __launch_bounds__(256) void xconv_k(const float* __restrict__ x,
                                               f16* __restrict__ xh) {
    const int i = blockIdx.x * 256 + threadIdx.x;   // i < NN*128/8 exactly
    const float4 a = reinterpret_cast<const float4*>(x)[i * 2];
    const float4 b = reinterpret_cast<const float4*>(x)[i * 2 + 1];
    union { f16 h[8]; float4 f4; } pk;
    pk.h[0] = (f16)a.x; pk.h[1] = (f16)a.y; pk.h[2] = (f16)a.z; pk.h[3] = (f16)a.w;
    pk.h[4] = (f16)b.x; pk.h[5] = (f16)b.y; pk.h[6] = (f16)b.z; pk.h[7] = (f16)b.w;
    reinterpret_cast<float4*>(xh)[i] = pk.f4;
}

// ---------------- W pre-convert: Wh[l][t][col][k] = (f16) W[l][t][k][col] ----------------
__global__ __launch_bounds__(256) void wconv3_k(const float* __restrict__ W0,
                                                const float* __restrict__ W1,
                                                const float* __restrict__ W2,
                                                f16* __restrict__ Wh) {
    const int l = blockIdx.z, t = blockIdx.y;
    const float* W = (l == 0) ? W0 : ((l == 1) ? W1 : W2);
    f16* Whl = Wh + (size_t)l * 2 * 16384;
    const int i0 = blockIdx.x * 2048;
    #pragma unroll
    for (int j = 0; j < 8; ++j) {
        const int i = i0 + threadIdx.x + j * 256;     // i = k*128 + col
        const int k = i >> 7, col = i & 127;
        Whl[t * 16384 + col * 128 + k] = (f16)W[t * 16384 + i];
    }
}

// ---------------- MFMA GEMM: feat16[t][n][:] = Ah @ W[t], fused el/er epilogue ----------------
#define APAD 136
__global__ __launch_bounds__(256) void gemm_mfma(const f16* __restrict__ Ah,
                                                 const f16* __restrict__ Whbase,
                                                 const float* __restrict__ albase,
                                                 const float* __restrict__ arbase,
                                                 f16* __restrict__ featbase,
                                                 float* __restrict__ elbase,
                                                 float* __restrict__ erbase) {
    __shared__ f16 Asl[64 * APAD];
    __shared__ f16 Bsl[128 * APAD];
    const int et = blockIdx.y;
    const f16* Wh = Whbase + et * 16384;
    f16* feat = featbase + (size_t)et * NN * 128;
    const int row0 = blockIdx.x * 64;
    const int t = threadIdx.x;

    #pragma unroll
    for (int j = 0; j < 4; ++j) {
        const int idx = t + j * 256;            // idx = row*16 + q
        const int r = idx >> 4, q = idx & 15;
        const int row = row0 + r;
        float4 v = make_float4(0.f, 0.f, 0.f, 0.f);
        if (row < NN) v = reinterpret_cast<const float4*>(Ah + (size_t)row * 128)[q];
        *reinterpret_cast<float4*>(&Asl[r * APAD + q * 8]) = v;
    }
    #pragma unroll
    for (int j = 0; j < 8; ++j) {
        const int idx = t + j * 256;            // idx = col*16 + k16
        const int col = idx >> 4, k16 = idx & 15;
        *reinterpret_cast<float4*>(&Bsl[col * APAD + k16 * 8]) =
            *reinterpret_cast<const float4*>(Wh + col * 128 + k16 * 8);
    }
    __syncthreads();

    const int w = t >> 6, lane = t & 63;
    const int r = lane & 15, g = lane >> 4;
    const int mb = w * 16;
    f32x4 acc[8];
    #pragma unroll
    for (int nt = 0; nt < 8; ++nt) acc[nt] = (f32x4){0.f, 0.f, 0.f, 0.f};

    #pragma unroll
    for (int ks = 0; ks < 4; ++ks) {
        const f16x8 av = *reinterpret_cast<const f16x8*>(&Asl[(mb + r) * APAD + ks * 32 + g * 8]);
        #pragma unroll
        for (int nt = 0; nt < 8; ++nt) {
            const f16x8 bv =
                *reinterpret_cast<const f16x8*>(&Bsl[(nt * 16 + r) * APAD + ks * 32 + g * 8]);
            acc[nt] = __builtin_amdgcn_mfma_f32_16x16x32_f16(av, bv, acc[nt], 0, 0, 0);
        }
    }

    float alv[8], arv[8];
    #pragma unroll
    for (int nt = 0; nt < 8; ++nt) {            // col = nt*16 + r
        alv[nt] = albase[et * 128 + nt * 16 + r];
        arv[nt] = arbase[et * 128 + nt * 16 + r];
    }
    #pragma unroll
    for (int p = 0; p < 4; ++p) {
        const int row = row0 + mb + g * 4 + p;
        const bool ok = row < NN;
        if (ok) {
            #pragma unroll
            for (int nt = 0; nt < 8; ++nt)
                feat[(size_t)row * 128 + nt * 16 + r] = (f16)acc[nt][p];
        }
        #pragma unroll
        for (int h = 0; h < 4; ++h) {
            float pl = fmaf(acc[2 * h][p], alv[2 * h], acc[2 * h + 1][p] * alv[2 * h + 1]);
            float pr = fmaf(acc[2 * h][p], arv[2 * h], acc[2 * h + 1][p] * arv[2 * h + 1]);
            pl += __shfl_xor(pl, 1); pl += __shfl_xor(pl, 2);
            pl += __shfl_xor(pl, 4); pl += __shfl_xor(pl, 8);
            pr += __shfl_xor(pr, 1); pr += __shfl_xor(pr, 2);
            pr += __shfl_xor(pr, 4); pr += __shfl_xor(pr, 8);
            if (ok && r == 0) {
                elbase[et * NN * HH + row * HH + h] = pl;
                erbase[et * NN * HH + row * HH + h] = pr;
            }
        }
    }
}

// ---------------- CSR build: histogram ----------------
__global__ __launch_bounds__(256) void hist_k(const int* __restrict__ dst0,
                                              const int* __restrict__ dst1,
                                              int* __restrict__ deg) {
    const int e = blockIdx.x * 256 + threadIdx.x;
    if (e >= EE) return;
    const int t = blockIdx.y;
    const int* d = t ? dst1 : dst0;
    atomicAdd(&deg[t * NN + d[e]], 1);
}

// ---------------- multi-block exclusive scan ----------------
__global__ __launch_bounds__(256) void scan1_k(const int* __restrict__ deg,
                                               int* __restrict__ offs,
                                               int* __restrict__ blocksum) {
    const int t = blockIdx.y, b = blockIdx.x;
    const int* d = deg + t * NN;
    int* o = offs + t * (NN + 1);
    const int base = b * 2048 + threadIdx.x * 8;
    int v[8];
    int s = 0;
    #pragma unroll
    for (int j = 0; j < 8; ++j) {
        const int i = base + j;
        v[j] = (i < NN) ? d[i] : 0;
        s += v[j];
    }
    __shared__ int buf[256];
    buf[threadIdx.x] = s;
    __syncthreads();
    #pragma unroll
    for (int ofs = 1; ofs < 256; ofs <<= 1) {
        const int add = (threadIdx.x >= (unsigned)ofs) ? buf[threadIdx.x - ofs] : 0;
        __syncthreads();
        buf[threadIdx.x] += add;
        __syncthreads();
    }
    int run = buf[threadIdx.x] - s;
    #pragma unroll
    for (int j = 0; j < 8; ++j) {
        const int i = base + j;
        if (i < NN) o[i] = run;
        run += v[j];
    }
    if (threadIdx.x == 255) blocksum[t * SCAN_NB + b] = buf[255];
}

__global__ __launch_bounds__(64) void scan2_k(int* __restrict__ blocksum,
                                              int* __restrict__ offs) {
    if (threadIdx.x != 0) return;
    #pragma unroll
    for (int t = 0; t < 2; ++t) {
        int run = 0;
        for (int b = 0; b < SCAN_NB; ++b) {
            const int v = blocksum[t * SCAN_NB + b];
            blocksum[t * SCAN_NB + b] = run;
            run += v;
        }
        offs[t * (NN + 1) + NN] = run;
    }
}

__global__ __launch_bounds__(256) void scan3_k(int* __restrict__ offs,
                                               const int* __restrict__ blocksum,
                                               int* __restrict__ cursor) {
    const int t = blockIdx.y, b = blockIdx.x;
    const int boff = blocksum[t * SCAN_NB + b];
    int* o = offs + t * (NN + 1);
    int* cur = cursor + t * NN;
    const int base = b * 2048 + threadIdx.x * 8;
    #pragma unroll
    for (int j = 0; j < 8; ++j) {
        const int i = base + j;
        if (i < NN) {
            const int val = o[i] + boff;
            o[i] = val;
            cur[i] = val;
        }
    }
}

// ---------------- scatter: single int2 (src,dst) write per CSR slot ----------------
__global__ __launch_bounds__(256) void scatter_k(const int* __restrict__ src0,
                                                 const int* __restrict__ dst0,
                                                 const int* __restrict__ src1,
                                                 const int* __restrict__ dst1,
                                                 int* __restrict__ cursor,
                                                 int2* __restrict__ csr2) {
    const int e = blockIdx.x * 256 + threadIdx.x;
    if (e >= EE) return;
    const int t = blockIdx.y;
    const int* s = t ? src1 : src0;
    const int* d = t ? dst1 : dst0;
    const int di = d[e];
    const int pos = atomicAdd(&cursor[t * NN + di], 1);
    csr2[(size_t)t * EE + pos] = make_int2(s[e], di);
}

// ---------------- edge-parallel softmax numerators: ex[t][slot][h] ----------------
__global__ __launch_bounds__(256) void edge_ex_k(const int2* __restrict__ csr2,
                                                 const float* __restrict__ el,
                                                 const float* __restrict__ er,
                                                 float* __restrict__ exf) {
    const int i = blockIdx.x * 256 + threadIdx.x;
    if (i >= EE) return;
    const int t = blockIdx.y;
    const int2 sd = csr2[(size_t)t * EE + i];
    const float4 l4 = *reinterpret_cast<const float4*>(el + t * NN * HH + sd.x * 4);
    const float4 r4 = *reinterpret_cast<const float4*>(er + t * NN * HH + sd.y * 4);
    float4 o;
    float v;
    v = l4.x + r4.x; v = (v >= 0.f) ? v : v * SLOPE; o.x = __expf(v);
    v = l4.y + r4.y; v = (v >= 0.f) ? v : v * SLOPE; o.y = __expf(v);
    v = l4.z + r4.z; v = (v >= 0.f) ? v : v * SLOPE; o.z = __expf(v);
    v = l4.w + r4.w; v = (v >= 0.f) ? v : v * SLOPE; o.w = __expf(v);
    *reinterpret_cast<float4*>(exf + (size_t)t * EE * 4 + (size_t)i * 4) = o;
}

// ---------------- pull aggregate: 2 waves per (node,etype), stride-2 deg split ----------------
// block = 4 waves = 1 node x 2 etypes x 2 halves; partial (s, x) combined in LDS.
__global__ __launch_bounds__(256) void pull_agg4_k(const int2* __restrict__ csr2,
                                                   const int* __restrict__ offs,
                                                   const float* __restrict__ exf,
                                                   const f16* __restrict__ feat,
                                                   const float* __restrict__ b0,
                                                   const float* __restrict__ b1,
                                                   f16* __restrict__ out, int relu) {
    __shared__ float xb[2][2][128];             // [etype][half][col] partial numerators
    __shared__ float sb[2][2][128];             // [etype][half][col] partial denominators
    const int w = threadIdx.x >> 6, lane = threadIdx.x & 63;
    const int t = w >> 1, u = w & 1;
    const int n = blockIdx.x;
    const int c0 = lane * 2;
    const int h = c0 >> 5;

    const int* so = offs + t * (NN + 1);
    const int e0 = so[n], e1 = so[n + 1];
    const int2* cs = csr2 + (size_t)t * EE;
    const float* ext = exf + (size_t)t * EE * 4;
    const f16* ft = feat + (size_t)t * NN * 128;
    float sA = 0.f, x0A = 0.f, x1A = 0.f;
    float sB = 0.f, x0B = 0.f, x1B = 0.f;
    float sC = 0.f, x0C = 0.f, x1C = 0.f;
    float sD = 0.f, x0D = 0.f, x1D = 0.f;
    int e = e0 + u;                              // this half's slots: e0+u, e0+u+2, ...
    for (; e + 6 < e1; e += 8) {
        const int sa = cs[e].x, sbi = cs[e + 2].x, sc = cs[e + 4].x, sd = cs[e + 6].x;
        const float ea = ext[(size_t)e * 4 + h];
        const float eb = ext[(size_t)(e + 2) * 4 + h];
        const float ec = ext[(size_t)(e + 4) * 4 + h];
        const float ed = ext[(size_t)(e + 6) * 4 + h];
        const f16x2 fa = *reinterpret_cast<const f16x2*>(ft + (size_t)sa * 128 + c0);
        const f16x2 fb = *reinterpret_cast<const f16x2*>(ft + (size_t)sbi * 128 + c0);
        const f16x2 fc = *reinterpret_cast<const f16x2*>(ft + (size_t)sc * 128 + c0);
        const f16x2 fd = *reinterpret_cast<const f16x2*>(ft + (size_t)sd * 128 + c0);
        sA += ea; x0A = fmaf(ea, (float)fa.x, x0A); x1A = fmaf(ea, (float)fa.y, x1A);
        sB += eb; x0B = fmaf(eb, (float)fb.x, x0B); x1B = fmaf(eb, (float)fb.y, x1B);
        sC += ec; x0C = fmaf(ec, (float)fc.x, x0C); x1C = fmaf(ec, (float)fc.y, x1C);
        sD += ed; x0D = fmaf(ed, (float)fd.x, x0D); x1D = fmaf(ed, (float)fd.y, x1D);
    }
    for (; e < e1; e += 2) {
        const int sa = cs[e].x;
        const float ea = ext[(size_t)e * 4 + h];
        const f16x2 fa = *reinterpret_cast<const f16x2*>(ft + (size_t)sa * 128 + c0);
        sA += ea; x0A = fmaf(ea, (float)fa.x, x0A); x1A = fmaf(ea, (float)fa.y, x1A);
    }
    xb[t][u][c0]     = (x0A + x0B) + (x0C + x0D);
    xb[t][u][c0 + 1] = (x1A + x1B) + (x1C + x1D);
    sb[t][u][c0]     = (sA + sB) + (sC + sD);
    __syncthreads();
    if (w == 0) {
        float a0 = b0[c0] + b1[c0];
        float a1 = b0[c0 + 1] + b1[c0 + 1];
        #pragma unroll
        for (int tt = 0; tt < 2; ++tt) {
            const float s = sb[tt][0][c0] + sb[tt][1][c0];
            const float inv = (s > 0.f) ? 1.f / s : 0.f;   // isolated node -> 0
            a0 = fmaf(xb[tt][0][c0] + xb[tt][1][c0], inv, a0);
            a1 = fmaf(xb[tt][0][c0 + 1] + xb[tt][1][c0 + 1], inv, a1);
        }
        if (relu) { a0 = fmaxf(a0, 0.f); a1 = fmaxf(a1, 0.f); }
        f16x2 o; o.x = (f16)a0; o.y = (f16)a1;
        *reinterpret_cast<f16x2*>(out + (size_t)n * 128 + c0) = o;
    }
}

// ---------------- final linear (f16 input) ----------------
__global__ __launch_bounds__(256) void out_gemm_k(const f16* __restrict__ A,
                                                  const float* __restrict__ W,
                                                  const float* __restrict__ bout,
                                                  float* __restrict__ out) {
    __shared__ float At[16][132];
    const int row0 = blockIdx.x * 16;   // NN % 16 == 0
    const int t = threadIdx.x;
    {
        const int r = t >> 4, c8 = t & 15;
        const f16x8 v = *reinterpret_cast<const f16x8*>(A + (size_t)(row0 + r) * 128 + c8 * 8);
        #pragma unroll
        for (int j = 0; j < 8; ++j) At[r][c8 * 8 + j] = (float)v[j];
    }
    __syncthreads();
    const int r = t >> 4, c = t & 15;
    float accv = 0.f;
    #pragma unroll 8
    for (int k = 0; k < 128; ++k) accv = fmaf(At[r][k], W[k * 16 + c], accv);
    out[(row0 + r) * 16 + c] = accv + bout[c];
}

extern "C" void kernel_launch(void* const* d_in, const int* in_sizes, int n_in,
                              void* d_out, int out_size, void* d_ws, size_t ws_size,
                              hipStream_t stream) {
    (void)in_sizes; (void)n_in; (void)out_size; (void)ws_size;
    const float* x = (const float*)d_in[0];
    const int* src0 = (const int*)d_in[1];
    const int* dst0 = (const int*)d_in[2];
    const int* src1 = (const int*)d_in[3];
    const int* dst1 = (const int*)d_in[4];
    const float* W[3]  = {(const float*)d_in[5], (const float*)d_in[9],  (const float*)d_in[13]};
    const float* al[3] = {(const float*)d_in[6], (const float*)d_in[10], (const float*)d_in[14]};
    const float* ar[3] = {(const float*)d_in[7], (const float*)d_in[11], (const float*)d_in[15]};
    const float* bb[3] = {(const float*)d_in[8], (const float*)d_in[12], (const float*)d_in[16]};
    const float* Wout = (const float*)d_in[17];
    const float* bout = (const float*)d_in[18];
    float* outp = (float*)d_out;

    char* pb = (char*)d_ws;
    f16* feat   = (f16*)pb;    pb += (size_t)2 * NN * 128 * 2;   // [2][NN][128] fp16
    f16* xh     = (f16*)pb;    pb += (size_t)NN * 128 * 2;
    f16* hbuf   = (f16*)pb;    pb += (size_t)NN * 128 * 2;
    float* el   = (float*)pb;  pb += (size_t)2 * NN * HH * 4;
    float* er   = (float*)pb;  pb += (size_t)2 * NN * HH * 4;
    int* deg    = (int*)pb;    pb += (size_t)2 * NN * 4;
    int* cursor = (int*)pb;    pb += (size_t)2 * NN * 4;
    int* offs   = (int*)pb;    pb += (size_t)2 * (NN + 1) * 4;
    int* bsum   = (int*)pb;    pb += (size_t)2 * SCAN_NB * 4;
    f16* Wh     = (f16*)pb;    pb += (size_t)3 * 2 * 128 * 128 * 2;
    int2* csr2  = (int2*)pb;   pb += (size_t)2 * EE * 8;
    float* exf  = (float*)pb;  pb += (size_t)2 * EE * HH * 4;

    // ---- CSR build + precompute (once per call) ----
    zero_k<<<(2 * NN / 4 + 255) / 256, 256, 0, stream>>>((int4*)deg, 2 * NN / 4);
    hist_k<<<dim3((EE + 255) / 256, 2), 256, 0, stream>>>(dst0, dst1, deg);
    scan1_k<<<dim3(SCAN_NB, 2), 256, 0, stream>>>(deg, offs, bsum);
    scan2_k<<<1, 64, 0, stream>>>(bsum, offs);
    scan3_k<<<dim3(SCAN_NB, 2), 256, 0, stream>>>(offs, bsum, cursor);
    scatter_k<<<dim3((EE + 255) / 256, 2), 256, 0, stream>>>(src0, dst0, src1, dst1,
                                                             cursor, csr2);
    wconv3_k<<<dim3(8, 2, 3), 256, 0, stream>>>(W[0], W[1], W[2], Wh);
    xconv_k<<<NN * 128 / 8 / 256, 256, 0, stream>>>(x, xh);

    // ---- 3 GAT layers ----
    const f16* hin = xh;
    for (int l = 0; l < 3; ++l) {
        gemm_mfma<<<dim3((NN + 63) / 64, 2), 256, 0, stream>>>(hin, Wh + l * 2 * 16384,
                                                               al[l], ar[l], feat, el, er);
        edge_ex_k<<<dim3((EE + 255) / 256, 2), 256, 0, stream>>>(csr2, el, er, exf);
        pull_agg4_k<<<NN, 256, 0, stream>>>(csr2, offs, exf, feat,
                                            bb[l], bb[l] + 128, hbuf, (l < 2) ? 1 : 0);
        hin = hbuf;
    }
    out_gemm_k<<<NN / 16, 256, 0, stream>>>(hbuf, Wout, bout, outp);
}

// Round 11
// 259.549 us; speedup vs baseline: 1.2296x; 1.2296x over previous
//
#include <hip/hip_runtime.h>

#define NN 30000
#define EE 300000
#define HH 4
#define SLOPE 0.2f
#define SCAN_NB 15        // ceil(30000 / 2048)

typedef _Float16 f16;
typedef f16 f16x8 __attribute__((ext_vector_type(8)));
typedef float f32x4 __attribute__((ext_vector_type(4)));

// ---------------- zero deg ----------------
__global__ __launch_bounds__(256) void zero_k(int4* __restrict__ p, int n4) {
    const int i = blockIdx.x * 256 + threadIdx.x;
    if (i < n4) p[i] = make_int4(0, 0, 0, 0);
}

// ---------------- x -> f16 (once per call) ----------------
__global__ __launch_bounds__(256) void xconv_k(const float* __restrict__ x,
                                               f16* __restrict__ xh) {
    const int i = blockIdx.x * 256 + threadIdx.x;   // i < NN*128/8 exactly
    const float4 a = reinterpret_cast<const float4*>(x)[i * 2];
    const float4 b = reinterpret_cast<const float4*>(x)[i * 2 + 1];
    union { f16 h[8]; float4 f4; } pk;
    pk.h[0] = (f16)a.x; pk.h[1] = (f16)a.y; pk.h[2] = (f16)a.z; pk.h[3] = (f16)a.w;
    pk.h[4] = (f16)b.x; pk.h[5] = (f16)b.y; pk.h[6] = (f16)b.z; pk.h[7] = (f16)b.w;
    reinterpret_cast<float4*>(xh)[i] = pk.f4;
}

// ---------------- W pre-convert: Wh[l][t][col][k] = (f16) W[l][t][k][col] ----------------
__global__ __launch_bounds__(256) void wconv3_k(const float* __restrict__ W0,
                                                const float* __restrict__ W1,
                                                const float* __restrict__ W2,
                                                f16* __restrict__ Wh) {
    const int l = blockIdx.z, t = blockIdx.y;
    const float* W = (l == 0) ? W0 : ((l == 1) ? W1 : W2);
    f16* Whl = Wh + (size_t)l * 2 * 16384;
    const int i0 = blockIdx.x * 2048;
    #pragma unroll
    for (int j = 0; j < 8; ++j) {
        const int i = i0 + threadIdx.x + j * 256;     // i = k*128 + col
        const int k = i >> 7, col = i & 127;
        Whl[t * 16384 + col * 128 + k] = (f16)W[t * 16384 + i];
    }
}

// ---------------- MFMA GEMM: feat16[t][n][:] = Ah @ W[t], fused el/er epilogue ----------------
#define APAD 136
__global__ __launch_bounds__(256) void gemm_mfma(const f16* __restrict__ Ah,
                                                 const f16* __restrict__ Whbase,
                                                 const float* __restrict__ albase,
                                                 const float* __restrict__ arbase,
                                                 f16* __restrict__ featbase,
                                                 float* __restrict__ elbase,
                                                 float* __restrict__ erbase) {
    __shared__ f16 Asl[64 * APAD];
    __shared__ f16 Bsl[128 * APAD];
    const int et = blockIdx.y;
    const f16* Wh = Whbase + et * 16384;
    f16* feat = featbase + (size_t)et * NN * 128;
    const int row0 = blockIdx.x * 64;
    const int t = threadIdx.x;

    #pragma unroll
    for (int j = 0; j < 4; ++j) {
        const int idx = t + j * 256;            // idx = row*16 + q
        const int r = idx >> 4, q = idx & 15;
        const int row = row0 + r;
        float4 v = make_float4(0.f, 0.f, 0.f, 0.f);
        if (row < NN) v = reinterpret_cast<const float4*>(Ah + (size_t)row * 128)[q];
        *reinterpret_cast<float4*>(&Asl[r * APAD + q * 8]) = v;
    }
    #pragma unroll
    for (int j = 0; j < 8; ++j) {
        const int idx = t + j * 256;            // idx = col*16 + k16
        const int col = idx >> 4, k16 = idx & 15;
        *reinterpret_cast<float4*>(&Bsl[col * APAD + k16 * 8]) =
            *reinterpret_cast<const float4*>(Wh + col * 128 + k16 * 8);
    }
    __syncthreads();

    const int w = t >> 6, lane = t & 63;
    const int r = lane & 15, g = lane >> 4;
    const int mb = w * 16;
    f32x4 acc[8];
    #pragma unroll
    for (int nt = 0; nt < 8; ++nt) acc[nt] = (f32x4){0.f, 0.f, 0.f, 0.f};

    #pragma unroll
    for (int ks = 0; ks < 4; ++ks) {
        const f16x8 av = *reinterpret_cast<const f16x8*>(&Asl[(mb + r) * APAD + ks * 32 + g * 8]);
        #pragma unroll
        for (int nt = 0; nt < 8; ++nt) {
            const f16x8 bv =
                *reinterpret_cast<const f16x8*>(&Bsl[(nt * 16 + r) * APAD + ks * 32 + g * 8]);
            acc[nt] = __builtin_amdgcn_mfma_f32_16x16x32_f16(av, bv, acc[nt], 0, 0, 0);
        }
    }

    float alv[8], arv[8];
    #pragma unroll
    for (int nt = 0; nt < 8; ++nt) {            // col = nt*16 + r
        alv[nt] = albase[et * 128 + nt * 16 + r];
        arv[nt] = arbase[et * 128 + nt * 16 + r];
    }
    #pragma unroll
    for (int p = 0; p < 4; ++p) {
        const int row = row0 + mb + g * 4 + p;
        const bool ok = row < NN;
        if (ok) {
            #pragma unroll
            for (int nt = 0; nt < 8; ++nt)
                feat[(size_t)row * 128 + nt * 16 + r] = (f16)acc[nt][p];
        }
        #pragma unroll
        for (int h = 0; h < 4; ++h) {
            float pl = fmaf(acc[2 * h][p], alv[2 * h], acc[2 * h + 1][p] * alv[2 * h + 1]);
            float pr = fmaf(acc[2 * h][p], arv[2 * h], acc[2 * h + 1][p] * arv[2 * h + 1]);
            pl += __shfl_xor(pl, 1); pl += __shfl_xor(pl, 2);
            pl += __shfl_xor(pl, 4); pl += __shfl_xor(pl, 8);
            pr += __shfl_xor(pr, 1); pr += __shfl_xor(pr, 2);
            pr += __shfl_xor(pr, 4); pr += __shfl_xor(pr, 8);
            if (ok && r == 0) {
                elbase[et * NN * HH + row * HH + h] = pl;
                erbase[et * NN * HH + row * HH + h] = pr;
            }
        }
    }
}

// ---------------- CSR build: histogram ----------------
__global__ __launch_bounds__(256) void hist_k(const int* __restrict__ dst0,
                                              const int* __restrict__ dst1,
                                              int* __restrict__ deg) {
    const int e = blockIdx.x * 256 + threadIdx.x;
    if (e >= EE) return;
    const int t = blockIdx.y;
    const int* d = t ? dst1 : dst0;
    atomicAdd(&deg[t * NN + d[e]], 1);
}

// ---------------- multi-block exclusive scan ----------------
__global__ __launch_bounds__(256) void scan1_k(const int* __restrict__ deg,
                                               int* __restrict__ offs,
                                               int* __restrict__ blocksum) {
    const int t = blockIdx.y, b = blockIdx.x;
    const int* d = deg + t * NN;
    int* o = offs + t * (NN + 1);
    const int base = b * 2048 + threadIdx.x * 8;
    int v[8];
    int s = 0;
    #pragma unroll
    for (int j = 0; j < 8; ++j) {
        const int i = base + j;
        v[j] = (i < NN) ? d[i] : 0;
        s += v[j];
    }
    __shared__ int buf[256];
    buf[threadIdx.x] = s;
    __syncthreads();
    #pragma unroll
    for (int ofs = 1; ofs < 256; ofs <<= 1) {
        const int add = (threadIdx.x >= (unsigned)ofs) ? buf[threadIdx.x - ofs] : 0;
        __syncthreads();
        buf[threadIdx.x] += add;
        __syncthreads();
    }
    int run = buf[threadIdx.x] - s;
    #pragma unroll
    for (int j = 0; j < 8; ++j) {
        const int i = base + j;
        if (i < NN) o[i] = run;
        run += v[j];
    }
    if (threadIdx.x == 255) blocksum[t * SCAN_NB + b] = buf[255];
}

__global__ __launch_bounds__(64) void scan2_k(int* __restrict__ blocksum,
                                              int* __restrict__ offs) {
    if (threadIdx.x != 0) return;
    #pragma unroll
    for (int t = 0; t < 2; ++t) {
        int run = 0;
        for (int b = 0; b < SCAN_NB; ++b) {
            const int v = blocksum[t * SCAN_NB + b];
            blocksum[t * SCAN_NB + b] = run;
            run += v;
        }
        offs[t * (NN + 1) + NN] = run;
    }
}

__global__ __launch_bounds__(256) void scan3_k(int* __restrict__ offs,
                                               const int* __restrict__ blocksum,
                                               int* __restrict__ cursor) {
    const int t = blockIdx.y, b = blockIdx.x;
    const int boff = blocksum[t * SCAN_NB + b];
    int* o = offs + t * (NN + 1);
    int* cur = cursor + t * NN;
    const int base = b * 2048 + threadIdx.x * 8;
    #pragma unroll
    for (int j = 0; j < 8; ++j) {
        const int i = base + j;
        if (i < NN) {
            const int val = o[i] + boff;
            o[i] = val;
            cur[i] = val;
        }
    }
}

// ---------------- scatter: single int (src) write per CSR slot ----------------
__global__ __launch_bounds__(256) void scatter_k(const int* __restrict__ src0,
                                                 const int* __restrict__ dst0,
                                                 const int* __restrict__ src1,
                                                 const int* __restrict__ dst1,
                                                 int* __restrict__ cursor,
                                                 int* __restrict__ csr_src) {
    const int e = blockIdx.x * 256 + threadIdx.x;
    if (e >= EE) return;
    const int t = blockIdx.y;
    const int* s = t ? src1 : src0;
    const int* d = t ? dst1 : dst0;
    const int pos = atomicAdd(&cursor[t * NN + d[e]], 1);
    csr_src[t * EE + pos] = s[e];
}

// ---------------- pull aggregate v5: 16 lanes/edge, 4 edges/wave-iter, fused exp ----------------
// block = 4 waves = 2 nodes x 2 etypes. lane = sub*16 + cg; cg covers cols cg*8..cg*8+7.
__global__ __launch_bounds__(256) void pull_agg5_k(const int* __restrict__ csr_src,
                                                   const int* __restrict__ offs,
                                                   const float* __restrict__ el,
                                                   const float* __restrict__ er,
                                                   const f16* __restrict__ feat,
                                                   const float* __restrict__ b0,
                                                   const float* __restrict__ b1,
                                                   f16* __restrict__ out, int relu) {
    __shared__ float xb[2][2][128];             // [node-parity][etype][col], normalized
    const int w = threadIdx.x >> 6, lane = threadIdx.x & 63;
    const int p = w >> 1, t = w & 1;
    const int n = blockIdx.x * 2 + p;           // NN even
    const int sub = lane >> 4;                  // edge slot within quad (0..3)
    const int cg = lane & 15;                   // col group
    const int h = cg >> 2;                      // head
    const int c0 = cg * 8;

    const int* so = offs + t * (NN + 1);
    const int e0 = so[n], e1 = so[n + 1];
    const int* cs = csr_src + t * EE;
    const float* elt = el + t * NN * HH;
    const float erh = er[t * NN * HH + n * HH + h];
    const f16* ft = feat + (size_t)t * NN * 128;

    float s = 0.f;
    float x[8];
    #pragma unroll
    for (int j = 0; j < 8; ++j) x[j] = 0.f;

    for (int eb = e0; eb < e1; eb += 4) {
        const int e = eb + sub;
        const bool valid = e < e1;
        const int si = cs[valid ? e : e0];      // fallback to a valid row
        float v = elt[si * HH + h] + erh;
        v = (v >= 0.f) ? v : v * SLOPE;
        float ex = __expf(v);
        ex = valid ? ex : 0.f;
        const f16x8 fr = *reinterpret_cast<const f16x8*>(ft + (size_t)si * 128 + c0);
        s += ex;
        #pragma unroll
        for (int j = 0; j < 8; ++j) x[j] = fmaf(ex, (float)fr[j], x[j]);
    }

    // combine across edge-sub lanes (bits 4,5)
    s += __shfl_xor(s, 16); s += __shfl_xor(s, 32);
    #pragma unroll
    for (int j = 0; j < 8; ++j) {
        x[j] += __shfl_xor(x[j], 16);
        x[j] += __shfl_xor(x[j], 32);
    }
    const float inv = (s > 0.f) ? 1.f / s : 0.f;    // isolated node -> 0, matches ref
    if (sub == 0) {
        float4 v0 = make_float4(x[0] * inv, x[1] * inv, x[2] * inv, x[3] * inv);
        float4 v1 = make_float4(x[4] * inv, x[5] * inv, x[6] * inv, x[7] * inv);
        *reinterpret_cast<float4*>(&xb[p][t][c0]) = v0;
        *reinterpret_cast<float4*>(&xb[p][t][c0 + 4]) = v1;
    }
    __syncthreads();
    if (t == 0) {
        const int c = lane * 2;
        float a0 = xb[p][0][c] + xb[p][1][c] + b0[c] + b1[c];
        float a1 = xb[p][0][c + 1] + xb[p][1][c + 1] + b0[c + 1] + b1[c + 1];
        if (relu) { a0 = fmaxf(a0, 0.f); a1 = fmaxf(a1, 0.f); }
        union { f16 h2[2]; float f; } o;
        o.h2[0] = (f16)a0; o.h2[1] = (f16)a1;
        *reinterpret_cast<float*>(out + (size_t)n * 128 + c) = o.f;
    }
}

// ---------------- final linear (f16 input) ----------------
__global__ __launch_bounds__(256) void out_gemm_k(const f16* __restrict__ A,
                                                  const float* __restrict__ W,
                                                  const float* __restrict__ bout,
                                                  float* __restrict__ out) {
    __shared__ float At[16][132];
    const int row0 = blockIdx.x * 16;   // NN % 16 == 0
    const int t = threadIdx.x;
    {
        const int r = t >> 4, c8 = t & 15;
        const f16x8 v = *reinterpret_cast<const f16x8*>(A + (size_t)(row0 + r) * 128 + c8 * 8);
        #pragma unroll
        for (int j = 0; j < 8; ++j) At[r][c8 * 8 + j] = (float)v[j];
    }
    __syncthreads();
    const int r = t >> 4, c = t & 15;
    float accv = 0.f;
    #pragma unroll 8
    for (int k = 0; k < 128; ++k) accv = fmaf(At[r][k], W[k * 16 + c], accv);
    out[(row0 + r) * 16 + c] = accv + bout[c];
}

extern "C" void kernel_launch(void* const* d_in, const int* in_sizes, int n_in,
                              void* d_out, int out_size, void* d_ws, size_t ws_size,
                              hipStream_t stream) {
    (void)in_sizes; (void)n_in; (void)out_size; (void)ws_size;
    const float* x = (const float*)d_in[0];
    const int* src0 = (const int*)d_in[1];
    const int* dst0 = (const int*)d_in[2];
    const int* src1 = (const int*)d_in[3];
    const int* dst1 = (const int*)d_in[4];
    const float* W[3]  = {(const float*)d_in[5], (const float*)d_in[9],  (const float*)d_in[13]};
    const float* al[3] = {(const float*)d_in[6], (const float*)d_in[10], (const float*)d_in[14]};
    const float* ar[3] = {(const float*)d_in[7], (const float*)d_in[11], (const float*)d_in[15]};
    const float* bb[3] = {(const float*)d_in[8], (const float*)d_in[12], (const float*)d_in[16]};
    const float* Wout = (const float*)d_in[17];
    const float* bout = (const float*)d_in[18];
    float* outp = (float*)d_out;

    char* pb = (char*)d_ws;
    f16* feat   = (f16*)pb;    pb += (size_t)2 * NN * 128 * 2;   // [2][NN][128] fp16
    f16* xh     = (f16*)pb;    pb += (size_t)NN * 128 * 2;
    f16* hbuf   = (f16*)pb;    pb += (size_t)NN * 128 * 2;
    float* el   = (float*)pb;  pb += (size_t)2 * NN * HH * 4;
    float* er   = (float*)pb;  pb += (size_t)2 * NN * HH * 4;
    int* deg    = (int*)pb;    pb += (size_t)2 * NN * 4;
    int* cursor = (int*)pb;    pb += (size_t)2 * NN * 4;
    int* offs   = (int*)pb;    pb += (size_t)2 * (NN + 1) * 4;
    int* bsum   = (int*)pb;    pb += (size_t)2 * SCAN_NB * 4;
    f16* Wh     = (f16*)pb;    pb += (size_t)3 * 2 * 128 * 128 * 2;
    int* csr    = (int*)pb;    pb += (size_t)2 * EE * 4;

    // ---- CSR build + precompute (once per call) ----
    zero_k<<<(2 * NN / 4 + 255) / 256, 256, 0, stream>>>((int4*)deg, 2 * NN / 4);
    hist_k<<<dim3((EE + 255) / 256, 2), 256, 0, stream>>>(dst0, dst1, deg);
    scan1_k<<<dim3(SCAN_NB, 2), 256, 0, stream>>>(deg, offs, bsum);
    scan2_k<<<1, 64, 0, stream>>>(bsum, offs);
    scan3_k<<<dim3(SCAN_NB, 2), 256, 0, stream>>>(offs, bsum, cursor);
    scatter_k<<<dim3((EE + 255) / 256, 2), 256, 0, stream>>>(src0, dst0, src1, dst1,
                                                             cursor, csr);
    wconv3_k<<<dim3(8, 2, 3), 256, 0, stream>>>(W[0], W[1], W[2], Wh);
    xconv_k<<<NN * 128 / 8 / 256, 256, 0, stream>>>(x, xh);

    // ---- 3 GAT layers ----
    const f16* hin = xh;
    for (int l = 0; l < 3; ++l) {
        gemm_mfma<<<dim3((NN + 63) / 64, 2), 256, 0, stream>>>(hin, Wh + l * 2 * 16384,
                                                               al[l], ar[l], feat, el, er);
        pull_agg5_k<<<NN / 2, 256, 0, stream>>>(csr, offs, el, er, feat,
                                                bb[l], bb[l] + 128, hbuf, (l < 2) ? 1 : 0);
        hin = hbuf;
    }
    out_gemm_k<<<NN / 16, 256, 0, stream>>>(hbuf, Wout, bout, outp);
}

// Round 12
// 244.167 us; speedup vs baseline: 1.3071x; 1.0630x over previous
//
#include <hip/hip_runtime.h>

#define NN 30000
#define EE 300000
#define HH 4
#define SLOPE 0.2f
#define SCAN_NB 15        // ceil(30000 / 2048)

typedef _Float16 f16;
typedef f16 f16x8 __attribute__((ext_vector_type(8)));
typedef float f32x4 __attribute__((ext_vector_type(4)));

// ---------------- zero deg ----------------
__global__ __launch_bounds__(256) void zero_k(int4* __restrict__ p, int n4) {
    const int i = blockIdx.x * 256 + threadIdx.x;
    if (i < n4) p[i] = make_int4(0, 0, 0, 0);
}

// ---------------- x -> f16 (once per call) ----------------
__global__ __launch_bounds__(256) void xconv_k(const float* __restrict__ x,
                                               f16* __restrict__ xh) {
    const int i = blockIdx.x * 256 + threadIdx.x;   // i < NN*128/8 exactly
    const float4 a = reinterpret_cast<const float4*>(x)[i * 2];
    const float4 b = reinterpret_cast<const float4*>(x)[i * 2 + 1];
    union { f16 h[8]; float4 f4; } pk;
    pk.h[0] = (f16)a.x; pk.h[1] = (f16)a.y; pk.h[2] = (f16)a.z; pk.h[3] = (f16)a.w;
    pk.h[4] = (f16)b.x; pk.h[5] = (f16)b.y; pk.h[6] = (f16)b.z; pk.h[7] = (f16)b.w;
    reinterpret_cast<float4*>(xh)[i] = pk.f4;
}

// ---------------- W pre-convert: Wh[l][t][col][k] = (f16) W[l][t][k][col] ----------------
__global__ __launch_bounds__(256) void wconv3_k(const float* __restrict__ W0,
                                                const float* __restrict__ W1,
                                                const float* __restrict__ W2,
                                                f16* __restrict__ Wh) {
    const int l = blockIdx.z, t = blockIdx.y;
    const float* W = (l == 0) ? W0 : ((l == 1) ? W1 : W2);
    f16* Whl = Wh + (size_t)l * 2 * 16384;
    const int i0 = blockIdx.x * 2048;
    #pragma unroll
    for (int j = 0; j < 8; ++j) {
        const int i = i0 + threadIdx.x + j * 256;     // i = k*128 + col
        const int k = i >> 7, col = i & 127;
        Whl[t * 16384 + col * 128 + k] = (f16)W[t * 16384 + i];
    }
}

// ---------------- MFMA GEMM: feat16[t][n][:] = Ah @ W[t], fused el/er epilogue ----------------
// A fragments loaded DIRECTLY from global (no cross-wave reuse -> LDS staging was pure
// occupancy loss: 52->35 KB LDS doubles blocks/CU).
#define APAD 136
__global__ __launch_bounds__(256) void gemm_mfma(const f16* __restrict__ Ah,
                                                 const f16* __restrict__ Whbase,
                                                 const float* __restrict__ albase,
                                                 const float* __restrict__ arbase,
                                                 f16* __restrict__ featbase,
                                                 float* __restrict__ elbase,
                                                 float* __restrict__ erbase) {
    __shared__ f16 Bsl[128 * APAD];
    const int et = blockIdx.y;
    const f16* Wh = Whbase + et * 16384;
    f16* feat = featbase + (size_t)et * NN * 128;
    const int row0 = blockIdx.x * 64;
    const int t = threadIdx.x;

    // stage B (Wh[col][k], 128 cols x 128 k f16 = 2048 float4s), 8 per thread
    #pragma unroll
    for (int j = 0; j < 8; ++j) {
        const int idx = t + j * 256;            // idx = col*16 + k16
        const int col = idx >> 4, k16 = idx & 15;
        *reinterpret_cast<float4*>(&Bsl[col * APAD + k16 * 8]) =
            *reinterpret_cast<const float4*>(Wh + col * 128 + k16 * 8);
    }
    __syncthreads();

    const int w = t >> 6, lane = t & 63;
    const int r = lane & 15, g = lane >> 4;
    const int mb = w * 16;
    const int rowa = min(row0 + mb + r, NN - 1);    // clamped A fragment row
    f32x4 acc[8];
    #pragma unroll
    for (int nt = 0; nt < 8; ++nt) acc[nt] = (f32x4){0.f, 0.f, 0.f, 0.f};

    #pragma unroll
    for (int ks = 0; ks < 4; ++ks) {
        const f16x8 av =
            *reinterpret_cast<const f16x8*>(Ah + (size_t)rowa * 128 + ks * 32 + g * 8);
        #pragma unroll
        for (int nt = 0; nt < 8; ++nt) {
            const f16x8 bv =
                *reinterpret_cast<const f16x8*>(&Bsl[(nt * 16 + r) * APAD + ks * 32 + g * 8]);
            acc[nt] = __builtin_amdgcn_mfma_f32_16x16x32_f16(av, bv, acc[nt], 0, 0, 0);
        }
    }

    float alv[8], arv[8];
    #pragma unroll
    for (int nt = 0; nt < 8; ++nt) {            // col = nt*16 + r
        alv[nt] = albase[et * 128 + nt * 16 + r];
        arv[nt] = arbase[et * 128 + nt * 16 + r];
    }
    #pragma unroll
    for (int p = 0; p < 4; ++p) {
        const int row = row0 + mb + g * 4 + p;
        const bool ok = row < NN;
        if (ok) {
            #pragma unroll
            for (int nt = 0; nt < 8; ++nt)
                feat[(size_t)row * 128 + nt * 16 + r] = (f16)acc[nt][p];
        }
        #pragma unroll
        for (int h = 0; h < 4; ++h) {
            float pl = fmaf(acc[2 * h][p], alv[2 * h], acc[2 * h + 1][p] * alv[2 * h + 1]);
            float pr = fmaf(acc[2 * h][p], arv[2 * h], acc[2 * h + 1][p] * arv[2 * h + 1]);
            pl += __shfl_xor(pl, 1); pl += __shfl_xor(pl, 2);
            pl += __shfl_xor(pl, 4); pl += __shfl_xor(pl, 8);
            pr += __shfl_xor(pr, 1); pr += __shfl_xor(pr, 2);
            pr += __shfl_xor(pr, 4); pr += __shfl_xor(pr, 8);
            if (ok && r == 0) {
                elbase[et * NN * HH + row * HH + h] = pl;
                erbase[et * NN * HH + row * HH + h] = pr;
            }
        }
    }
}

// ---------------- CSR build: histogram ----------------
__global__ __launch_bounds__(256) void hist_k(const int* __restrict__ dst0,
                                              const int* __restrict__ dst1,
                                              int* __restrict__ deg) {
    const int e = blockIdx.x * 256 + threadIdx.x;
    if (e >= EE) return;
    const int t = blockIdx.y;
    const int* d = t ? dst1 : dst0;
    atomicAdd(&deg[t * NN + d[e]], 1);
}

// ---------------- multi-block exclusive scan ----------------
__global__ __launch_bounds__(256) void scan1_k(const int* __restrict__ deg,
                                               int* __restrict__ offs,
                                               int* __restrict__ blocksum) {
    const int t = blockIdx.y, b = blockIdx.x;
    const int* d = deg + t * NN;
    int* o = offs + t * (NN + 1);
    const int base = b * 2048 + threadIdx.x * 8;
    int v[8];
    int s = 0;
    #pragma unroll
    for (int j = 0; j < 8; ++j) {
        const int i = base + j;
        v[j] = (i < NN) ? d[i] : 0;
        s += v[j];
    }
    __shared__ int buf[256];
    buf[threadIdx.x] = s;
    __syncthreads();
    #pragma unroll
    for (int ofs = 1; ofs < 256; ofs <<= 1) {
        const int add = (threadIdx.x >= (unsigned)ofs) ? buf[threadIdx.x - ofs] : 0;
        __syncthreads();
        buf[threadIdx.x] += add;
        __syncthreads();
    }
    int run = buf[threadIdx.x] - s;
    #pragma unroll
    for (int j = 0; j < 8; ++j) {
        const int i = base + j;
        if (i < NN) o[i] = run;
        run += v[j];
    }
    if (threadIdx.x == 255) blocksum[t * SCAN_NB + b] = buf[255];
}

__global__ __launch_bounds__(64) void scan2_k(int* __restrict__ blocksum,
                                              int* __restrict__ offs) {
    if (threadIdx.x != 0) return;
    #pragma unroll
    for (int t = 0; t < 2; ++t) {
        int run = 0;
        for (int b = 0; b < SCAN_NB; ++b) {
            const int v = blocksum[t * SCAN_NB + b];
            blocksum[t * SCAN_NB + b] = run;
            run += v;
        }
        offs[t * (NN + 1) + NN] = run;
    }
}

__global__ __launch_bounds__(256) void scan3_k(int* __restrict__ offs,
                                               const int* __restrict__ blocksum,
                                               int* __restrict__ cursor) {
    const int t = blockIdx.y, b = blockIdx.x;
    const int boff = blocksum[t * SCAN_NB + b];
    int* o = offs + t * (NN + 1);
    int* cur = cursor + t * NN;
    const int base = b * 2048 + threadIdx.x * 8;
    #pragma unroll
    for (int j = 0; j < 8; ++j) {
        const int i = base + j;
        if (i < NN) {
            const int val = o[i] + boff;
            o[i] = val;
            cur[i] = val;
        }
    }
}

// ---------------- scatter: single int (src) write per CSR slot ----------------
__global__ __launch_bounds__(256) void scatter_k(const int* __restrict__ src0,
                                                 const int* __restrict__ dst0,
                                                 const int* __restrict__ src1,
                                                 const int* __restrict__ dst1,
                                                 int* __restrict__ cursor,
                                                 int* __restrict__ csr_src) {
    const int e = blockIdx.x * 256 + threadIdx.x;
    if (e >= EE) return;
    const int t = blockIdx.y;
    const int* s = t ? src1 : src0;
    const int* d = t ? dst1 : dst0;
    const int pos = atomicAdd(&cursor[t * NN + d[e]], 1);
    csr_src[t * EE + pos] = s[e];
}

// ---------------- pull aggregate v6: 16 lanes/edge, 4 edges/iter, depth-1 pipeline ----------------
// block = 4 waves = 2 nodes x 2 etypes. lane = sub*16 + cg; cg covers cols cg*8..cg*8+7.
// Next quad's src indices are prefetched before consuming the current quad, breaking the
// cs->elt/feat dependent chain that throttled v5.
__global__ __launch_bounds__(256) void pull_agg6_k(const int* __restrict__ csr_src,
                                                   const int* __restrict__ offs,
                                                   const float* __restrict__ el,
                                                   const float* __restrict__ er,
                                                   const f16* __restrict__ feat,
                                                   const float* __restrict__ b0,
                                                   const float* __restrict__ b1,
                                                   f16* __restrict__ out, int relu) {
    __shared__ float xb[2][2][128];             // [node-parity][etype][col], normalized
    const int w = threadIdx.x >> 6, lane = threadIdx.x & 63;
    const int p = w >> 1, t = w & 1;
    const int n = blockIdx.x * 2 + p;           // NN even
    const int sub = lane >> 4;                  // edge slot within quad (0..3)
    const int cg = lane & 15;                   // col group
    const int h = cg >> 2;                      // head
    const int c0 = cg * 8;

    const int* so = offs + t * (NN + 1);
    const int e0 = so[n], e1 = so[n + 1];

    float s = 0.f;
    float x[8];
    #pragma unroll
    for (int j = 0; j < 8; ++j) x[j] = 0.f;

    if (e0 < e1) {
        const int* cs = csr_src + t * EE;
        const float* elt = el + t * NN * HH;
        const float erh = er[t * NN * HH + n * HH + h];
        const f16* ft = feat + (size_t)t * NN * 128;
        const int elast = e1 - 1;

        int e = e0 + sub;
        bool val_a = e < e1;
        int si_a = cs[min(e, elast)];
        for (int eb = e0; eb < e1; eb += 4) {
            const int en = eb + 4 + sub;
            const bool val_b = en < e1;
            const int si_b = cs[min(en, elast)];       // prefetch next quad's src index
            const float lv = elt[si_a * HH + h];
            const f16x8 fr = *reinterpret_cast<const f16x8*>(ft + (size_t)si_a * 128 + c0);
            float v = lv + erh;
            v = (v >= 0.f) ? v : v * SLOPE;
            float ex = __expf(v);
            ex = val_a ? ex : 0.f;
            s += ex;
            #pragma unroll
            for (int j = 0; j < 8; ++j) x[j] = fmaf(ex, (float)fr[j], x[j]);
            si_a = si_b; val_a = val_b;
        }
    }

    // combine across edge-sub lanes (bits 4,5)
    s += __shfl_xor(s, 16); s += __shfl_xor(s, 32);
    #pragma unroll
    for (int j = 0; j < 8; ++j) {
        x[j] += __shfl_xor(x[j], 16);
        x[j] += __shfl_xor(x[j], 32);
    }
    const float inv = (s > 0.f) ? 1.f / s : 0.f;    // isolated node -> 0, matches ref
    if (sub == 0) {
        float4 v0 = make_float4(x[0] * inv, x[1] * inv, x[2] * inv, x[3] * inv);
        float4 v1 = make_float4(x[4] * inv, x[5] * inv, x[6] * inv, x[7] * inv);
        *reinterpret_cast<float4*>(&xb[p][t][c0]) = v0;
        *reinterpret_cast<float4*>(&xb[p][t][c0 + 4]) = v1;
    }
    __syncthreads();
    if (t == 0) {
        const int c = lane * 2;
        float a0 = xb[p][0][c] + xb[p][1][c] + b0[c] + b1[c];
        float a1 = xb[p][0][c + 1] + xb[p][1][c + 1] + b0[c + 1] + b1[c + 1];
        if (relu) { a0 = fmaxf(a0, 0.f); a1 = fmaxf(a1, 0.f); }
        union { f16 h2[2]; float f; } o;
        o.h2[0] = (f16)a0; o.h2[1] = (f16)a1;
        *reinterpret_cast<float*>(out + (size_t)n * 128 + c) = o.f;
    }
}

// ---------------- final linear (f16 input) ----------------
__global__ __launch_bounds__(256) void out_gemm_k(const f16* __restrict__ A,
                                                  const float* __restrict__ W,
                                                  const float* __restrict__ bout,
                                                  float* __restrict__ out) {
    __shared__ float At[16][132];
    const int row0 = blockIdx.x * 16;   // NN % 16 == 0
    const int t = threadIdx.x;
    {
        const int r = t >> 4, c8 = t & 15;
        const f16x8 v = *reinterpret_cast<const f16x8*>(A + (size_t)(row0 + r) * 128 + c8 * 8);
        #pragma unroll
        for (int j = 0; j < 8; ++j) At[r][c8 * 8 + j] = (float)v[j];
    }
    __syncthreads();
    const int r = t >> 4, c = t & 15;
    float accv = 0.f;
    #pragma unroll 8
    for (int k = 0; k < 128; ++k) accv = fmaf(At[r][k], W[k * 16 + c], accv);
    out[(row0 + r) * 16 + c] = accv + bout[c];
}

extern "C" void kernel_launch(void* const* d_in, const int* in_sizes, int n_in,
                              void* d_out, int out_size, void* d_ws, size_t ws_size,
                              hipStream_t stream) {
    (void)in_sizes; (void)n_in; (void)out_size; (void)ws_size;
    const float* x = (const float*)d_in[0];
    const int* src0 = (const int*)d_in[1];
    const int* dst0 = (const int*)d_in[2];
    const int* src1 = (const int*)d_in[3];
    const int* dst1 = (const int*)d_in[4];
    const float* W[3]  = {(const float*)d_in[5], (const float*)d_in[9],  (const float*)d_in[13]};
    const float* al[3] = {(const float*)d_in[6], (const float*)d_in[10], (const float*)d_in[14]};
    const float* ar[3] = {(const float*)d_in[7], (const float*)d_in[11], (const float*)d_in[15]};
    const float* bb[3] = {(const float*)d_in[8], (const float*)d_in[12], (const float*)d_in[16]};
    const float* Wout = (const float*)d_in[17];
    const float* bout = (const float*)d_in[18];
    float* outp = (float*)d_out;

    char* pb = (char*)d_ws;
    f16* feat   = (f16*)pb;    pb += (size_t)2 * NN * 128 * 2;   // [2][NN][128] fp16
    f16* xh     = (f16*)pb;    pb += (size_t)NN * 128 * 2;
    f16* hbuf   = (f16*)pb;    pb += (size_t)NN * 128 * 2;
    float* el   = (float*)pb;  pb += (size_t)2 * NN * HH * 4;
    float* er   = (float*)pb;  pb += (size_t)2 * NN * HH * 4;
    int* deg    = (int*)pb;    pb += (size_t)2 * NN * 4;
    int* cursor = (int*)pb;    pb += (size_t)2 * NN * 4;
    int* offs   = (int*)pb;    pb += (size_t)2 * (NN + 1) * 4;
    int* bsum   = (int*)pb;    pb += (size_t)2 * SCAN_NB * 4;
    f16* Wh     = (f16*)pb;    pb += (size_t)3 * 2 * 128 * 128 * 2;
    int* csr    = (int*)pb;    pb += (size_t)2 * EE * 4;

    // ---- CSR build + precompute (once per call) ----
    zero_k<<<(2 * NN / 4 + 255) / 256, 256, 0, stream>>>((int4*)deg, 2 * NN / 4);
    hist_k<<<dim3((EE + 255) / 256, 2), 256, 0, stream>>>(dst0, dst1, deg);
    scan1_k<<<dim3(SCAN_NB, 2), 256, 0, stream>>>(deg, offs, bsum);
    scan2_k<<<1, 64, 0, stream>>>(bsum, offs);
    scan3_k<<<dim3(SCAN_NB, 2), 256, 0, stream>>>(offs, bsum, cursor);
    scatter_k<<<dim3((EE + 255) / 256, 2), 256, 0, stream>>>(src0, dst0, src1, dst1,
                                                             cursor, csr);
    wconv3_k<<<dim3(8, 2, 3), 256, 0, stream>>>(W[0], W[1], W[2], Wh);
    xconv_k<<<NN * 128 / 8 / 256, 256, 0, stream>>>(x, xh);

    // ---- 3 GAT layers ----
    const f16* hin = xh;
    for (int l = 0; l < 3; ++l) {
        gemm_mfma<<<dim3((NN + 63) / 64, 2), 256, 0, stream>>>(hin, Wh + l * 2 * 16384,
                                                               al[l], ar[l], feat, el, er);
        pull_agg6_k<<<NN / 2, 256, 0, stream>>>(csr, offs, el, er, feat,
                                                bb[l], bb[l] + 128, hbuf, (l < 2) ? 1 : 0);
        hin = hbuf;
    }
    out_gemm_k<<<NN / 16, 256, 0, stream>>>(hbuf, Wout, bout, outp);
}

// Round 13
// 230.286 us; speedup vs baseline: 1.3859x; 1.0603x over previous
//
#include <hip/hip_runtime.h>

#define NN 30000
#define EE 300000
#define HH 4
#define SLOPE 0.2f
#define SCAN_NB 15        // ceil(30000 / 2048)

typedef _Float16 f16;
typedef f16 f16x8 __attribute__((ext_vector_type(8)));
typedef float f32x4 __attribute__((ext_vector_type(4)));

// ---------------- zero deg ----------------
__global__ __launch_bounds__(256) void zero_k(int4* __restrict__ p, int n4) {
    const int i = blockIdx.x * 256 + threadIdx.x;
    if (i < n4) p[i] = make_int4(0, 0, 0, 0);
}

// ---------------- W pre-convert: Wh[l][t][col][k] = (f16) W[l][t][k][col] ----------------
__global__ __launch_bounds__(256) void wconv3_k(const float* __restrict__ W0,
                                                const float* __restrict__ W1,
                                                const float* __restrict__ W2,
                                                f16* __restrict__ Wh) {
    const int l = blockIdx.z, t = blockIdx.y;
    const float* W = (l == 0) ? W0 : ((l == 1) ? W1 : W2);
    f16* Whl = Wh + (size_t)l * 2 * 16384;
    const int i0 = blockIdx.x * 2048;
    #pragma unroll
    for (int j = 0; j < 8; ++j) {
        const int i = i0 + threadIdx.x + j * 256;     // i = k*128 + col
        const int k = i >> 7, col = i & 127;
        Whl[t * 16384 + col * 128 + k] = (f16)W[t * 16384 + i];
    }
}

// ---------------- MFMA GEMM: feat16[t][n][:] = A @ W[t], fused el/er epilogue ----------------
// A fragments loaded DIRECTLY from global (no cross-wave reuse). Layer 1 reads f32 x and
// converts in registers (use_f32=1), removing the separate xconv pass.
#define APAD 136
__global__ __launch_bounds__(256) void gemm_mfma(const f16* __restrict__ Ah,
                                                 const float* __restrict__ Af,
                                                 const int use_f32,
                                                 const f16* __restrict__ Whbase,
                                                 const float* __restrict__ albase,
                                                 const float* __restrict__ arbase,
                                                 f16* __restrict__ featbase,
                                                 float* __restrict__ elbase,
                                                 float* __restrict__ erbase) {
    __shared__ f16 Bsl[128 * APAD];
    const int et = blockIdx.y;
    const f16* Wh = Whbase + et * 16384;
    f16* feat = featbase + (size_t)et * NN * 128;
    const int row0 = blockIdx.x * 64;
    const int t = threadIdx.x;

    // stage B (Wh[col][k], 128 cols x 128 k f16 = 2048 float4s), 8 per thread
    #pragma unroll
    for (int j = 0; j < 8; ++j) {
        const int idx = t + j * 256;            // idx = col*16 + k16
        const int col = idx >> 4, k16 = idx & 15;
        *reinterpret_cast<float4*>(&Bsl[col * APAD + k16 * 8]) =
            *reinterpret_cast<const float4*>(Wh + col * 128 + k16 * 8);
    }
    __syncthreads();

    const int w = t >> 6, lane = t & 63;
    const int r = lane & 15, g = lane >> 4;
    const int mb = w * 16;
    const int rowa = min(row0 + mb + r, NN - 1);    // clamped A fragment row
    f32x4 acc[8];
    #pragma unroll
    for (int nt = 0; nt < 8; ++nt) acc[nt] = (f32x4){0.f, 0.f, 0.f, 0.f};

    #pragma unroll
    for (int ks = 0; ks < 4; ++ks) {
        f16x8 av;
        if (use_f32) {
            const float4 a0 =
                *reinterpret_cast<const float4*>(Af + (size_t)rowa * 128 + ks * 32 + g * 8);
            const float4 a1 =
                *reinterpret_cast<const float4*>(Af + (size_t)rowa * 128 + ks * 32 + g * 8 + 4);
            av[0] = (f16)a0.x; av[1] = (f16)a0.y; av[2] = (f16)a0.z; av[3] = (f16)a0.w;
            av[4] = (f16)a1.x; av[5] = (f16)a1.y; av[6] = (f16)a1.z; av[7] = (f16)a1.w;
        } else {
            av = *reinterpret_cast<const f16x8*>(Ah + (size_t)rowa * 128 + ks * 32 + g * 8);
        }
        #pragma unroll
        for (int nt = 0; nt < 8; ++nt) {
            const f16x8 bv =
                *reinterpret_cast<const f16x8*>(&Bsl[(nt * 16 + r) * APAD + ks * 32 + g * 8]);
            acc[nt] = __builtin_amdgcn_mfma_f32_16x16x32_f16(av, bv, acc[nt], 0, 0, 0);
        }
    }

    float alv[8], arv[8];
    #pragma unroll
    for (int nt = 0; nt < 8; ++nt) {            // col = nt*16 + r
        alv[nt] = albase[et * 128 + nt * 16 + r];
        arv[nt] = arbase[et * 128 + nt * 16 + r];
    }
    #pragma unroll
    for (int p = 0; p < 4; ++p) {
        const int row = row0 + mb + g * 4 + p;
        const bool ok = row < NN;
        if (ok) {
            #pragma unroll
            for (int nt = 0; nt < 8; ++nt)
                feat[(size_t)row * 128 + nt * 16 + r] = (f16)acc[nt][p];
        }
        #pragma unroll
        for (int h = 0; h < 4; ++h) {
            float pl = fmaf(acc[2 * h][p], alv[2 * h], acc[2 * h + 1][p] * alv[2 * h + 1]);
            float pr = fmaf(acc[2 * h][p], arv[2 * h], acc[2 * h + 1][p] * arv[2 * h + 1]);
            pl += __shfl_xor(pl, 1); pl += __shfl_xor(pl, 2);
            pl += __shfl_xor(pl, 4); pl += __shfl_xor(pl, 8);
            pr += __shfl_xor(pr, 1); pr += __shfl_xor(pr, 2);
            pr += __shfl_xor(pr, 4); pr += __shfl_xor(pr, 8);
            if (ok && r == 0) {
                elbase[et * NN * HH + row * HH + h] = pl;
                erbase[et * NN * HH + row * HH + h] = pr;
            }
        }
    }
}

// ---------------- CSR build: histogram ----------------
__global__ __launch_bounds__(256) void hist_k(const int* __restrict__ dst0,
                                              const int* __restrict__ dst1,
                                              int* __restrict__ deg) {
    const int e = blockIdx.x * 256 + threadIdx.x;
    if (e >= EE) return;
    const int t = blockIdx.y;
    const int* d = t ? dst1 : dst0;
    atomicAdd(&deg[t * NN + d[e]], 1);
}

// ---------------- multi-block exclusive scan ----------------
__global__ __launch_bounds__(256) void scan1_k(const int* __restrict__ deg,
                                               int* __restrict__ offs,
                                               int* __restrict__ blocksum) {
    const int t = blockIdx.y, b = blockIdx.x;
    const int* d = deg + t * NN;
    int* o = offs + t * (NN + 1);
    const int base = b * 2048 + threadIdx.x * 8;
    int v[8];
    int s = 0;
    #pragma unroll
    for (int j = 0; j < 8; ++j) {
        const int i = base + j;
        v[j] = (i < NN) ? d[i] : 0;
        s += v[j];
    }
    __shared__ int buf[256];
    buf[threadIdx.x] = s;
    __syncthreads();
    #pragma unroll
    for (int ofs = 1; ofs < 256; ofs <<= 1) {
        const int add = (threadIdx.x >= (unsigned)ofs) ? buf[threadIdx.x - ofs] : 0;
        __syncthreads();
        buf[threadIdx.x] += add;
        __syncthreads();
    }
    int run = buf[threadIdx.x] - s;
    #pragma unroll
    for (int j = 0; j < 8; ++j) {
        const int i = base + j;
        if (i < NN) o[i] = run;
        run += v[j];
    }
    if (threadIdx.x == 255) blocksum[t * SCAN_NB + b] = buf[255];
}

__global__ __launch_bounds__(64) void scan2_k(int* __restrict__ blocksum,
                                              int* __restrict__ offs) {
    if (threadIdx.x != 0) return;
    #pragma unroll
    for (int t = 0; t < 2; ++t) {
        int run = 0;
        for (int b = 0; b < SCAN_NB; ++b) {
            const int v = blocksum[t * SCAN_NB + b];
            blocksum[t * SCAN_NB + b] = run;
            run += v;
        }
        offs[t * (NN + 1) + NN] = run;
    }
}

__global__ __launch_bounds__(256) void scan3_k(int* __restrict__ offs,
                                               const int* __restrict__ blocksum,
                                               int* __restrict__ cursor) {
    const int t = blockIdx.y, b = blockIdx.x;
    const int boff = blocksum[t * SCAN_NB + b];
    int* o = offs + t * (NN + 1);
    int* cur = cursor + t * NN;
    const int base = b * 2048 + threadIdx.x * 8;
    #pragma unroll
    for (int j = 0; j < 8; ++j) {
        const int i = base + j;
        if (i < NN) {
            const int val = o[i] + boff;
            o[i] = val;
            cur[i] = val;
        }
    }
}

// ---------------- scatter: single int (src) write per CSR slot ----------------
__global__ __launch_bounds__(256) void scatter_k(const int* __restrict__ src0,
                                                 const int* __restrict__ dst0,
                                                 const int* __restrict__ src1,
                                                 const int* __restrict__ dst1,
                                                 int* __restrict__ cursor,
                                                 int* __restrict__ csr_src) {
    const int e = blockIdx.x * 256 + threadIdx.x;
    if (e >= EE) return;
    const int t = blockIdx.y;
    const int* s = t ? src1 : src0;
    const int* d = t ? dst1 : dst0;
    const int pos = atomicAdd(&cursor[t * NN + d[e]], 1);
    csr_src[t * EE + pos] = s[e];
}

// ---------------- pull aggregate v7: depth-2 index / depth-1 data pipeline ----------------
// block = 4 waves = 2 nodes x 2 etypes. lane = sub*16 + cg; cg covers cols cg*8..cg*8+7.
// Iteration q: issue cs for quad q+2; issue elt/feat for quad q+1 (index arrived last iter);
// compute quad q from registers. No load waits on a same-iteration load.
__global__ __launch_bounds__(256) void pull_agg7_k(const int* __restrict__ csr_src,
                                                   const int* __restrict__ offs,
                                                   const float* __restrict__ el,
                                                   const float* __restrict__ er,
                                                   const f16* __restrict__ feat,
                                                   const float* __restrict__ b0,
                                                   const float* __restrict__ b1,
                                                   f16* __restrict__ out, int relu) {
    __shared__ float xb[2][2][128];             // [node-parity][etype][col], normalized
    const int w = threadIdx.x >> 6, lane = threadIdx.x & 63;
    const int p = w >> 1, t = w & 1;
    const int n = blockIdx.x * 2 + p;           // NN even
    const int sub = lane >> 4;                  // edge slot within quad (0..3)
    const int cg = lane & 15;                   // col group
    const int h = cg >> 2;                      // head
    const int c0 = cg * 8;

    const int* so = offs + t * (NN + 1);
    const int e0 = so[n], e1 = so[n + 1];

    float s = 0.f;
    float x[8];
    #pragma unroll
    for (int j = 0; j < 8; ++j) x[j] = 0.f;

    if (e0 < e1) {
        const int* cs = csr_src + t * EE;
        const float* elt = el + t * NN * HH;
        const float erh = er[t * NN * HH + n * HH + h];
        const f16* ft = feat + (size_t)t * NN * 128;
        const int elast = e1 - 1;

        // prologue: quad 0 index+data, quad 1 index
        int si_0 = cs[min(e0 + sub, elast)];
        int si_1 = cs[min(e0 + 4 + sub, elast)];
        float lv_0 = elt[si_0 * HH + h];
        f16x8 fr_0 = *reinterpret_cast<const f16x8*>(ft + (size_t)si_0 * 128 + c0);

        for (int eb = e0; eb < e1; eb += 4) {
            // issue index for quad q+2
            const int si_2 = cs[min(eb + 8 + sub, elast)];
            // issue data for quad q+1
            const float lv_1 = elt[si_1 * HH + h];
            const f16x8 fr_1 = *reinterpret_cast<const f16x8*>(ft + (size_t)si_1 * 128 + c0);
            // compute quad q
            float v = lv_0 + erh;
            v = (v >= 0.f) ? v : v * SLOPE;
            float ex = __expf(v);
            ex = (eb + sub < e1) ? ex : 0.f;
            s += ex;
            #pragma unroll
            for (int j = 0; j < 8; ++j) x[j] = fmaf(ex, (float)fr_0[j], x[j]);
            // rotate
            si_1 = si_2; lv_0 = lv_1; fr_0 = fr_1;
        }
    }

    // combine across edge-sub lanes (bits 4,5)
    s += __shfl_xor(s, 16); s += __shfl_xor(s, 32);
    #pragma unroll
    for (int j = 0; j < 8; ++j) {
        x[j] += __shfl_xor(x[j], 16);
        x[j] += __shfl_xor(x[j], 32);
    }
    const float inv = (s > 0.f) ? 1.f / s : 0.f;    // isolated node -> 0, matches ref
    if (sub == 0) {
        float4 v0 = make_float4(x[0] * inv, x[1] * inv, x[2] * inv, x[3] * inv);
        float4 v1 = make_float4(x[4] * inv, x[5] * inv, x[6] * inv, x[7] * inv);
        *reinterpret_cast<float4*>(&xb[p][t][c0]) = v0;
        *reinterpret_cast<float4*>(&xb[p][t][c0 + 4]) = v1;
    }
    __syncthreads();
    if (t == 0) {
        const int c = lane * 2;
        float a0 = xb[p][0][c] + xb[p][1][c] + b0[c] + b1[c];
        float a1 = xb[p][0][c + 1] + xb[p][1][c + 1] + b0[c + 1] + b1[c + 1];
        if (relu) { a0 = fmaxf(a0, 0.f); a1 = fmaxf(a1, 0.f); }
        union { f16 h2[2]; float f; } o;
        o.h2[0] = (f16)a0; o.h2[1] = (f16)a1;
        *reinterpret_cast<float*>(out + (size_t)n * 128 + c) = o.f;
    }
}

// ---------------- final linear (f16 input) ----------------
__global__ __launch_bounds__(256) void out_gemm_k(const f16* __restrict__ A,
                                                  const float* __restrict__ W,
                                                  const float* __restrict__ bout,
                                                  float* __restrict__ out) {
    __shared__ float At[16][132];
    const int row0 = blockIdx.x * 16;   // NN % 16 == 0
    const int t = threadIdx.x;
    {
        const int r = t >> 4, c8 = t & 15;
        const f16x8 v = *reinterpret_cast<const f16x8*>(A + (size_t)(row0 + r) * 128 + c8 * 8);
        #pragma unroll
        for (int j = 0; j < 8; ++j) At[r][c8 * 8 + j] = (float)v[j];
    }
    __syncthreads();
    const int r = t >> 4, c = t & 15;
    float accv = 0.f;
    #pragma unroll 8
    for (int k = 0; k < 128; ++k) accv = fmaf(At[r][k], W[k * 16 + c], accv);
    out[(row0 + r) * 16 + c] = accv + bout[c];
}

extern "C" void kernel_launch(void* const* d_in, const int* in_sizes, int n_in,
                              void* d_out, int out_size, void* d_ws, size_t ws_size,
                              hipStream_t stream) {
    (void)in_sizes; (void)n_in; (void)out_size; (void)ws_size;
    const float* x = (const float*)d_in[0];
    const int* src0 = (const int*)d_in[1];
    const int* dst0 = (const int*)d_in[2];
    const int* src1 = (const int*)d_in[3];
    const int* dst1 = (const int*)d_in[4];
    const float* W[3]  = {(const float*)d_in[5], (const float*)d_in[9],  (const float*)d_in[13]};
    const float* al[3] = {(const float*)d_in[6], (const float*)d_in[10], (const float*)d_in[14]};
    const float* ar[3] = {(const float*)d_in[7], (const float*)d_in[11], (const float*)d_in[15]};
    const float* bb[3] = {(const float*)d_in[8], (const float*)d_in[12], (const float*)d_in[16]};
    const float* Wout = (const float*)d_in[17];
    const float* bout = (const float*)d_in[18];
    float* outp = (float*)d_out;

    char* pb = (char*)d_ws;
    f16* feat   = (f16*)pb;    pb += (size_t)2 * NN * 128 * 2;   // [2][NN][128] fp16
    f16* hbuf   = (f16*)pb;    pb += (size_t)NN * 128 * 2;
    float* el   = (float*)pb;  pb += (size_t)2 * NN * HH * 4;
    float* er   = (float*)pb;  pb += (size_t)2 * NN * HH * 4;
    int* deg    = (int*)pb;    pb += (size_t)2 * NN * 4;
    int* cursor = (int*)pb;    pb += (size_t)2 * NN * 4;
    int* offs   = (int*)pb;    pb += (size_t)2 * (NN + 1) * 4;
    int* bsum   = (int*)pb;    pb += (size_t)2 * SCAN_NB * 4;
    f16* Wh     = (f16*)pb;    pb += (size_t)3 * 2 * 128 * 128 * 2;
    int* csr    = (int*)pb;    pb += (size_t)2 * EE * 4;

    // ---- CSR build + precompute (once per call) ----
    zero_k<<<(2 * NN / 4 + 255) / 256, 256, 0, stream>>>((int4*)deg, 2 * NN / 4);
    hist_k<<<dim3((EE + 255) / 256, 2), 256, 0, stream>>>(dst0, dst1, deg);
    scan1_k<<<dim3(SCAN_NB, 2), 256, 0, stream>>>(deg, offs, bsum);
    scan2_k<<<1, 64, 0, stream>>>(bsum, offs);
    scan3_k<<<dim3(SCAN_NB, 2), 256, 0, stream>>>(offs, bsum, cursor);
    scatter_k<<<dim3((EE + 255) / 256, 2), 256, 0, stream>>>(src0, dst0, src1, dst1,
                                                             cursor, csr);
    wconv3_k<<<dim3(8, 2, 3), 256, 0, stream>>>(W[0], W[1], W[2], Wh);

    // ---- 3 GAT layers ----
    const f16* hin = hbuf;
    for (int l = 0; l < 3; ++l) {
        gemm_mfma<<<dim3((NN + 63) / 64, 2), 256, 0, stream>>>(
            hin, x, (l == 0) ? 1 : 0, Wh + l * 2 * 16384, al[l], ar[l], feat, el, er);
        pull_agg7_k<<<NN / 2, 256, 0, stream>>>(csr, offs, el, er, feat,
                                                bb[l], bb[l] + 128, hbuf, (l < 2) ? 1 : 0);
        hin = hbuf;
    }
    out_gemm_k<<<NN / 16, 256, 0, stream>>>(hbuf, Wout, bout, outp);
}